// Round 7
// baseline (534.176 us; speedup 1.0000x reference)
//
#include <hip/hip_runtime.h>
#include <hip/hip_bf16.h>
#include <math.h>

#define B_   32
#define CIN  3
#define H_   224
#define W_   224
#define OC   192
#define OH   112
#define OW   112
#define PH   56
#define PW   56
#define NSP  (B_*OH*OW)          // 401408 elements per channel for BN stats
#define PLANE (OH*OW)            // 12544

static __device__ __forceinline__ unsigned short f2bf(float f) {
    __hip_bfloat16 h = __float2bfloat16(f);   // RNE
    return *reinterpret_cast<unsigned short*>(&h);
}
// bf16 pair unpack from a packed uint (lo = bits[15:0], hi = bits[31:16])
static __device__ __forceinline__ float bf_lo(unsigned int u) {
    unsigned int v = u << 16;
    return *reinterpret_cast<float*>(&v);
}
static __device__ __forceinline__ float bf_hi(unsigned int u) {
    unsigned int v = u & 0xffff0000u;
    return *reinterpret_cast<float*>(&v);
}

static __device__ __forceinline__ float fexp2(float x) {
#if __has_builtin(__builtin_amdgcn_exp2f)
    return __builtin_amdgcn_exp2f(x);
#else
    return exp2f(x);
#endif
}
static __device__ __forceinline__ float frcp(float x) {
#if __has_builtin(__builtin_amdgcn_rcpf)
    return __builtin_amdgcn_rcpf(x);
#else
    return 1.0f / x;
#endif
}

// tanh-form GELU: x * sigmoid(2*c1*(x + 0.044715 x^3)), via exp2 (+rcp).
static __device__ __forceinline__ float fast_gelu(float x) {
    float x2 = x * x;
    float inner = fmaf(0.044715f * x2, x, x);
    float e = fexp2(inner * 2.3022082f);      // 2*0.7978845608*log2(e)
    float r = frcp(1.0f + e);
    return x * (e * r);
}

// ---------------- K0: zero the stats accumulators (ws is poisoned 0xAA) ----
__global__ void zero_stats(float* stats) {
    for (int i = threadIdx.x; i < 384; i += 256) stats[i] = 0.f;
}

// ---------------- K1: conv 3x3 s2 p1 + bias ------------------------------
// Thread: 4 consecutive ow (ushort4 store) x 48 ocs (oc split 4).
// Grid: 4 ocg x 28 owg x 14 spatial = 1568 blocks x 256 (6.1/CU, balanced).
// Taps: 3 aligned float4 per (c,r): iw0 = 8*owg-1, s = 8*owg-4 (owg>0) ->
// compile-time offset 3. owg is BLOCK-uniform -> edge branch non-divergent.
__global__ __launch_bounds__(256) void conv_kernel(
    const float* __restrict__ x, const float* __restrict__ w,
    const float* __restrict__ bias, __hip_bfloat16* __restrict__ y)
{
    int bx  = blockIdx.x;
    int ocg = bx & 3;
    int rem = bx >> 2;
    int owg = rem % 28;                          // block-uniform
    int sb  = rem / 28;                          // 0..13
    int pos = sb * 256 + threadIdx.x;            // 0..3583
    int oh  = pos % OH;
    int b   = pos / OH;

    int ih0 = 2 * oh - 1;

    float taps[CIN][3][9];
    if (owg > 0) {
        int s = 8 * owg - 4;
        #pragma unroll
        for (int c = 0; c < CIN; ++c) {
            #pragma unroll
            for (int r = 0; r < 3; ++r) {
                int ih = ih0 + r;
                bool rv = (ih >= 0) && (ih < H_);
                const float* base =
                    x + (((size_t)b * CIN + c) * H_ + (rv ? ih : 0)) * W_ + s;
                float4 L0 = *reinterpret_cast<const float4*>(base);
                float4 L1 = *reinterpret_cast<const float4*>(base + 4);
                float4 L2 = *reinterpret_cast<const float4*>(base + 8);
                float L[12] = {L0.x, L0.y, L0.z, L0.w, L1.x, L1.y, L1.z, L1.w,
                               L2.x, L2.y, L2.z, L2.w};
                #pragma unroll
                for (int j = 0; j < 9; ++j)
                    taps[c][r][j] = rv ? L[3 + j] : 0.f;   // col iw0+j = s+3+j
            }
        }
    } else {                                     // owg == 0: iw0 = -1
        #pragma unroll
        for (int c = 0; c < CIN; ++c) {
            #pragma unroll
            for (int r = 0; r < 3; ++r) {
                int ih = ih0 + r;
                bool rv = (ih >= 0) && (ih < H_);
                const float* base =
                    x + (((size_t)b * CIN + c) * H_ + (rv ? ih : 0)) * W_;
                float4 L0 = *reinterpret_cast<const float4*>(base);
                float4 L1 = *reinterpret_cast<const float4*>(base + 4);
                float L[8] = {L0.x, L0.y, L0.z, L0.w, L1.x, L1.y, L1.z, L1.w};
                taps[c][r][0] = 0.f;             // col -1 = padding
                #pragma unroll
                for (int j = 1; j < 9; ++j)
                    taps[c][r][j] = rv ? L[j - 1] : 0.f;
            }
        }
    }

    int oc0 = ocg * 48;
    unsigned short* yp = reinterpret_cast<unsigned short*>(y) +
                         ((size_t)b * OC + oc0) * PLANE + oh * OW + 4 * owg;

    #pragma unroll 2
    for (int l = 0; l < 48; ++l) {
        int oc = oc0 + l;                        // uniform -> scalar w/bias path
        float bs = bias[oc];
        float a0 = bs, a1 = bs, a2 = bs, a3 = bs;
        const float* wp = w + oc * 27;
        #pragma unroll
        for (int c = 0; c < CIN; ++c)
            #pragma unroll
            for (int r = 0; r < 3; ++r)
                #pragma unroll
                for (int k = 0; k < 3; ++k) {
                    float wv = wp[c * 9 + r * 3 + k];
                    a0 = fmaf(wv, taps[c][r][k + 0], a0);
                    a1 = fmaf(wv, taps[c][r][k + 2], a1);
                    a2 = fmaf(wv, taps[c][r][k + 4], a2);
                    a3 = fmaf(wv, taps[c][r][k + 6], a3);
                }
        ushort4 p;
        p.x = f2bf(a0); p.y = f2bf(a1); p.z = f2bf(a2); p.w = f2bf(a3);
        *reinterpret_cast<ushort4*>(yp + (size_t)l * PLANE) = p;
    }
}

// ---------------- K2: per-channel sum / sumsq over y (BW-saturated) -------
__global__ __launch_bounds__(256) void stats_kernel(
    const __hip_bfloat16* __restrict__ y, float* __restrict__ stats)
{
    int plane = blockIdx.x;            // b*OC + oc, 6144 blocks
    int oc = plane % OC;
    const unsigned int* p =
        reinterpret_cast<const unsigned int*>(y) + plane * (PLANE / 2);

    float s = 0.f, s2 = 0.f;
    for (int ch = threadIdx.x; ch < PLANE / 8; ch += 256) {
        uint4 v = reinterpret_cast<const uint4*>(p)[ch];
        unsigned int u[4] = {v.x, v.y, v.z, v.w};
        #pragma unroll
        for (int k = 0; k < 4; ++k) {
            float lo = bf_lo(u[k]);
            float hi = bf_hi(u[k]);
            s  += lo + hi;
            s2 += lo * lo + hi * hi;
        }
    }

    __shared__ float ls[256], ls2[256];
    int tid = threadIdx.x;
    ls[tid] = s; ls2[tid] = s2;
    __syncthreads();
    for (int off = 128; off > 0; off >>= 1) {
        if (tid < off) { ls[tid] += ls[tid + off]; ls2[tid] += ls2[tid + off]; }
        __syncthreads();
    }
    if (tid == 0) {
        atomicAdd(&stats[oc], ls[0]);
        atomicAdd(&stats[OC + oc], ls2[0]);
    }
}

// ---------------- K3: min/max pool (2 rows x 8 cols per thread) -----------
// Per input row: 3 aligned uint4 loads (24 bf16, cols 16j-8..16j+15; used
// 16j-1..16j+15), per-output-col 3-wide min/max, merged into 2x8 running
// extremes. Then 1 affine + 2 fast-GELU per output (GELU unimodal).
__global__ __launch_bounds__(256) void pool_kernel(
    const __hip_bfloat16* __restrict__ y, const float* __restrict__ stats,
    const float* __restrict__ gamma, const float* __restrict__ beta,
    float* __restrict__ out)
{
    int g = blockIdx.x * 256 + threadIdx.x;     // 1,204,224 total
    int j = g % 7;                              // 8-col out group
    int t = g / 7;
    int i = t % 28;                             // 2-row out group
    int plane = t / 28;                         // b*OC + oc
    int oc = plane % OC;

    const unsigned short* py =
        reinterpret_cast<const unsigned short*>(y) + (size_t)plane * PLANE;

    float owmin[2][8], owmax[2][8];
    #pragma unroll
    for (int kk = 0; kk < 2; ++kk)
        #pragma unroll
        for (int m = 0; m < 8; ++m) { owmin[kk][m] = INFINITY; owmax[kk][m] = -INFINITY; }

    #pragma unroll
    for (int r = 0; r < 5; ++r) {
        int ih = 4 * i - 1 + r;                 // only i==0,r==0 can be <0
        if (ih >= 0) {
            const uint4* rp = reinterpret_cast<const uint4*>(py + ih * OW + 16 * j - 8);
            uint4 u0 = rp[0], u1 = rp[1], u2 = rp[2];
            float L[24];
            L[0]=bf_lo(u0.x); L[1]=bf_hi(u0.x); L[2]=bf_lo(u0.y); L[3]=bf_hi(u0.y);
            L[4]=bf_lo(u0.z); L[5]=bf_hi(u0.z); L[6]=bf_lo(u0.w); L[7]=bf_hi(u0.w);
            L[8]=bf_lo(u1.x); L[9]=bf_hi(u1.x); L[10]=bf_lo(u1.y); L[11]=bf_hi(u1.y);
            L[12]=bf_lo(u1.z); L[13]=bf_hi(u1.z); L[14]=bf_lo(u1.w); L[15]=bf_hi(u1.w);
            L[16]=bf_lo(u2.x); L[17]=bf_hi(u2.x); L[18]=bf_lo(u2.y); L[19]=bf_hi(u2.y);
            L[20]=bf_lo(u2.z); L[21]=bf_hi(u2.z); L[22]=bf_lo(u2.w); L[23]=bf_hi(u2.w);

            // col 16j-1 (L[7]) is OOB for j==0 -> neutral values
            float l7min = (j == 0) ? INFINITY  : L[7];
            float l7max = (j == 0) ? -INFINITY : L[7];

            float hwmin[8], hwmax[8];
            hwmin[0] = fminf(fminf(l7min, L[8]), L[9]);
            hwmax[0] = fmaxf(fmaxf(l7max, L[8]), L[9]);
            #pragma unroll
            for (int m = 1; m < 8; ++m) {
                hwmin[m] = fminf(fminf(L[7 + 2*m], L[8 + 2*m]), L[9 + 2*m]);
                hwmax[m] = fmaxf(fmaxf(L[7 + 2*m], L[8 + 2*m]), L[9 + 2*m]);
            }

            // out row kk uses input rows r = 2kk..2kk+2
            #pragma unroll
            for (int m = 0; m < 8; ++m) {
                if (r <= 2) {                    // rows 0,1,2 -> kk=0
                    owmin[0][m] = fminf(owmin[0][m], hwmin[m]);
                    owmax[0][m] = fmaxf(owmax[0][m], hwmax[m]);
                }
                if (r >= 2) {                    // rows 2,3,4 -> kk=1
                    owmin[1][m] = fminf(owmin[1][m], hwmin[m]);
                    owmax[1][m] = fmaxf(owmax[1][m], hwmax[m]);
                }
            }
        }
    }

    float mean = stats[oc] * (1.0f / (float)NSP);
    float var  = fmaf(-mean, mean, stats[OC + oc] * (1.0f / (float)NSP));
    float inv  = rsqrtf(var + 1e-5f);
    float sc   = gamma[oc] * inv;
    float sh   = fmaf(-mean, sc, beta[oc]);

    float* ob = out + (size_t)plane * (PH * PW) + (2 * i) * PW + 8 * j;
    #pragma unroll
    for (int kk = 0; kk < 2; ++kk) {
        float res[8];
        #pragma unroll
        for (int m = 0; m < 8; ++m) {
            float lo = fmaf(owmin[kk][m], sc, sh);
            float hi = fmaf(owmax[kk][m], sc, sh);
            res[m] = fmaxf(fast_gelu(lo), fast_gelu(hi));
        }
        float4 r0 = {res[0], res[1], res[2], res[3]};
        float4 r1 = {res[4], res[5], res[6], res[7]};
        *reinterpret_cast<float4*>(ob + kk * PW)     = r0;
        *reinterpret_cast<float4*>(ob + kk * PW + 4) = r1;
    }
}

extern "C" void kernel_launch(void* const* d_in, const int* in_sizes, int n_in,
                              void* d_out, int out_size, void* d_ws, size_t ws_size,
                              hipStream_t stream) {
    const float* x     = (const float*)d_in[0];
    const float* w     = (const float*)d_in[1];
    const float* bias  = (const float*)d_in[2];
    const float* gamma = (const float*)d_in[3];
    const float* beta  = (const float*)d_in[4];
    float* out = (float*)d_out;

    float* stats = (float*)d_ws;                                   // 384 floats of sums
    __hip_bfloat16* y = (__hip_bfloat16*)((char*)d_ws + 4096);     // 154.1 MB bf16

    hipLaunchKernelGGL(zero_stats, dim3(1), dim3(256), 0, stream, stats);
    hipLaunchKernelGGL(conv_kernel, dim3(4 * 28 * 14), dim3(256), 0, stream,
                       x, w, bias, y);
    hipLaunchKernelGGL(stats_kernel, dim3(B_ * OC), dim3(256), 0, stream, y, stats);
    hipLaunchKernelGGL(pool_kernel, dim3(B_ * OC * PH * PW / 16 / 256), dim3(256), 0,
                       stream, y, stats, gamma, beta, out);
}

// Round 8
// 234.523 us; speedup vs baseline: 2.2777x; 2.2777x over previous
//
#include <hip/hip_runtime.h>
#include <hip/hip_bf16.h>
#include <math.h>

#define B_   32
#define CIN  3
#define H_   224
#define W_   224
#define OC   192
#define OH   112
#define OW   112
#define PH   56
#define PW   56
#define NSP  (B_*OH*OW)          // 401408 elements per channel for BN stats
#define PLANE (OH*OW)            // 12544
#define OCG  4                   // oc split in conv
#define OCPG (OC / OCG)          // 48 ocs per thread

static __device__ __forceinline__ unsigned short f2bf(float f) {
    __hip_bfloat16 h = __float2bfloat16(f);   // RNE
    return *reinterpret_cast<unsigned short*>(&h);
}
// bf16 pair unpack from a packed uint (lo = bits[15:0], hi = bits[31:16])
static __device__ __forceinline__ float bf_lo(unsigned int u) {
    unsigned int v = u << 16;
    return *reinterpret_cast<float*>(&v);
}
static __device__ __forceinline__ float bf_hi(unsigned int u) {
    unsigned int v = u & 0xffff0000u;
    return *reinterpret_cast<float*>(&v);
}

static __device__ __forceinline__ float fexp2(float x) {
#if __has_builtin(__builtin_amdgcn_exp2f)
    return __builtin_amdgcn_exp2f(x);
#else
    return exp2f(x);
#endif
}
static __device__ __forceinline__ float frcp(float x) {
#if __has_builtin(__builtin_amdgcn_rcpf)
    return __builtin_amdgcn_rcpf(x);
#else
    return 1.0f / x;
#endif
}

// tanh-form GELU: x * sigmoid(2*c1*(x + 0.044715 x^3)), via exp2 (+rcp).
// Unimodal (single minimum at x ~ -0.75).
static __device__ __forceinline__ float fast_gelu(float x) {
    float x2 = x * x;
    float inner = fmaf(0.044715f * x2, x, x);
    float e = fexp2(inner * 2.3022082f);      // 2*0.7978845608*log2(e)
    float r = frcp(1.0f + e);
    return x * (e * r);
}

// ---------------- K0: zero the stats accumulators (ws is poisoned 0xAA) ----
__global__ void zero_stats(float* stats) {
    for (int i = threadIdx.x; i < 384; i += 256) stats[i] = 0.f;
}

// ---------------- K1: conv 3x3 s2 p1 + bias ------------------------------
// Thread: 4 consecutive ow (ushort4 store) x 48 ocs. LANES take CONSECUTIVE
// owg -> wave stores are contiguous (512B). Grid: 4 ocg x 392 spatial = 1568.
// Taps: iw0 = 8*owg-1; base s = 8*owg-4 is 16B-aligned PER LANE; 3 float4
// loads, uniform extraction taps[j] = L[3+j]; owg==0 only needs taps[0]=0.
__global__ __launch_bounds__(256) void conv_kernel(
    const float* __restrict__ x, const float* __restrict__ w,
    const float* __restrict__ bias, __hip_bfloat16* __restrict__ y)
{
    int ocg = blockIdx.x / 392;                  // block-uniform
    int sg  = (blockIdx.x - ocg * 392) * 256 + threadIdx.x;  // 0..100351
    int owg = sg % 28;                           // per-lane, consecutive
    int t   = sg / 28;
    int oh  = t % OH;
    int b   = t / OH;

    int ih0 = 2 * oh - 1;
    int s   = (owg > 0) ? (8 * owg - 4) : 0;     // 16B-aligned per lane

    float taps[CIN][3][9];
    #pragma unroll
    for (int c = 0; c < CIN; ++c) {
        #pragma unroll
        for (int r = 0; r < 3; ++r) {
            int ih = ih0 + r;
            bool rv = (ih >= 0) && (ih < H_);
            const float* base =
                x + (((size_t)b * CIN + c) * H_ + (rv ? ih : 0)) * W_;
            float4 La = *reinterpret_cast<const float4*>(base + s);
            float4 Lb = *reinterpret_cast<const float4*>(base + (8 * owg));
            float4 Lc = *reinterpret_cast<const float4*>(base + (8 * owg + 4));
            float L[12] = {La.x, La.y, La.z, La.w, Lb.x, Lb.y, Lb.z, Lb.w,
                           Lc.x, Lc.y, Lc.z, Lc.w};
            #pragma unroll
            for (int j = 0; j < 9; ++j)
                taps[c][r][j] = rv ? L[3 + j] : 0.f;   // col iw0+j
            if (owg == 0) taps[c][r][0] = 0.f;         // col -1 = padding
        }
    }

    int oc0 = ocg * OCPG;
    unsigned short* yp = reinterpret_cast<unsigned short*>(y) +
                         ((size_t)b * OC + oc0) * PLANE + oh * OW + 4 * owg;

    #pragma unroll 2
    for (int l = 0; l < OCPG; ++l) {
        int oc = oc0 + l;                        // uniform -> scalar w/bias path
        float bs = bias[oc];
        float a0 = bs, a1 = bs, a2 = bs, a3 = bs;
        const float* wp = w + oc * 27;
        #pragma unroll
        for (int c = 0; c < CIN; ++c)
            #pragma unroll
            for (int r = 0; r < 3; ++r)
                #pragma unroll
                for (int k = 0; k < 3; ++k) {
                    float wv = wp[c * 9 + r * 3 + k];
                    a0 = fmaf(wv, taps[c][r][k + 0], a0);
                    a1 = fmaf(wv, taps[c][r][k + 2], a1);
                    a2 = fmaf(wv, taps[c][r][k + 4], a2);
                    a3 = fmaf(wv, taps[c][r][k + 6], a3);
                }
        ushort4 p;
        p.x = f2bf(a0); p.y = f2bf(a1); p.z = f2bf(a2); p.w = f2bf(a3);
        *reinterpret_cast<ushort4*>(yp + (size_t)l * PLANE) = p;
    }
}

// ---------------- K2: per-channel sum / sumsq over y (BW-saturated) -------
__global__ __launch_bounds__(256) void stats_kernel(
    const __hip_bfloat16* __restrict__ y, float* __restrict__ stats)
{
    int plane = blockIdx.x;            // b*OC + oc, 6144 blocks
    int oc = plane % OC;
    const unsigned int* p =
        reinterpret_cast<const unsigned int*>(y) + plane * (PLANE / 2);

    float s = 0.f, s2 = 0.f;
    for (int ch = threadIdx.x; ch < PLANE / 8; ch += 256) {
        uint4 v = reinterpret_cast<const uint4*>(p)[ch];
        unsigned int u[4] = {v.x, v.y, v.z, v.w};
        #pragma unroll
        for (int k = 0; k < 4; ++k) {
            float lo = bf_lo(u[k]);
            float hi = bf_hi(u[k]);
            s  += lo + hi;
            s2 += lo * lo + hi * hi;
        }
    }

    __shared__ float ls[256], ls2[256];
    int tid = threadIdx.x;
    ls[tid] = s; ls2[tid] = s2;
    __syncthreads();
    for (int off = 128; off > 0; off >>= 1) {
        if (tid < off) { ls[tid] += ls[tid + off]; ls2[tid] += ls2[tid + off]; }
        __syncthreads();
    }
    if (tid == 0) {
        atomicAdd(&stats[oc], ls[0]);
        atomicAdd(&stats[OC + oc], ls2[0]);
    }
}

// ---------------- K3: min/max pool (1 row x 8 cols per thread) ------------
// Per input row: 3 aligned uint4 loads (cols 16j-8..16j+15; used 16j-1..+15),
// running col min/max over 3 rows, then per output 1 affine + 2 fast-GELU
// (GELU unimodal). 2.4M threads for deep latency hiding.
__global__ __launch_bounds__(256) void pool_kernel(
    const __hip_bfloat16* __restrict__ y, const float* __restrict__ stats,
    const float* __restrict__ gamma, const float* __restrict__ beta,
    float* __restrict__ out)
{
    int g = blockIdx.x * 256 + threadIdx.x;     // 2,408,448 total
    int j = g % 7;                              // 8-col out group, lane-consecutive
    int t = g / 7;
    int ph = t % PH;
    int plane = t / PH;                         // b*OC + oc
    int oc = plane % OC;

    const unsigned short* py =
        reinterpret_cast<const unsigned short*>(y) + (size_t)plane * PLANE;

    float cmin[8], cmax[8];
    #pragma unroll
    for (int m = 0; m < 8; ++m) { cmin[m] = INFINITY; cmax[m] = -INFINITY; }

    #pragma unroll
    for (int rr = 0; rr < 3; ++rr) {
        int ih = 2 * ph - 1 + rr;               // <0 only for ph==0,rr==0; <=111 always
        if (ih >= 0) {
            const uint4* rp = reinterpret_cast<const uint4*>(py + ih * OW + 16 * j - 8);
            uint4 u0 = rp[0], u1 = rp[1], u2 = rp[2];
            float L[24];
            L[0]=bf_lo(u0.x); L[1]=bf_hi(u0.x); L[2]=bf_lo(u0.y); L[3]=bf_hi(u0.y);
            L[4]=bf_lo(u0.z); L[5]=bf_hi(u0.z); L[6]=bf_lo(u0.w); L[7]=bf_hi(u0.w);
            L[8]=bf_lo(u1.x); L[9]=bf_hi(u1.x); L[10]=bf_lo(u1.y); L[11]=bf_hi(u1.y);
            L[12]=bf_lo(u1.z); L[13]=bf_hi(u1.z); L[14]=bf_lo(u1.w); L[15]=bf_hi(u1.w);
            L[16]=bf_lo(u2.x); L[17]=bf_hi(u2.x); L[18]=bf_lo(u2.y); L[19]=bf_hi(u2.y);
            L[20]=bf_lo(u2.z); L[21]=bf_hi(u2.z); L[22]=bf_lo(u2.w); L[23]=bf_hi(u2.w);

            // L[7] = col 16j-1: OOB for j==0 -> neutral
            float l7min = (j == 0) ? INFINITY  : L[7];
            float l7max = (j == 0) ? -INFINITY : L[7];

            cmin[0] = fminf(cmin[0], fminf(fminf(l7min, L[8]), L[9]));
            cmax[0] = fmaxf(cmax[0], fmaxf(fmaxf(l7max, L[8]), L[9]));
            #pragma unroll
            for (int m = 1; m < 8; ++m) {
                cmin[m] = fminf(cmin[m], fminf(fminf(L[7+2*m], L[8+2*m]), L[9+2*m]));
                cmax[m] = fmaxf(cmax[m], fmaxf(fmaxf(L[7+2*m], L[8+2*m]), L[9+2*m]));
            }
        }
    }

    float mean = stats[oc] * (1.0f / (float)NSP);
    float var  = fmaf(-mean, mean, stats[OC + oc] * (1.0f / (float)NSP));
    float inv  = rsqrtf(var + 1e-5f);
    float sc   = gamma[oc] * inv;
    float sh   = fmaf(-mean, sc, beta[oc]);

    float res[8];
    #pragma unroll
    for (int m = 0; m < 8; ++m) {
        float lo = fmaf(cmin[m], sc, sh);
        float hi = fmaf(cmax[m], sc, sh);
        res[m] = fmaxf(fast_gelu(lo), fast_gelu(hi));
    }

    float* ob = out + (size_t)plane * (PH * PW) + ph * PW + 8 * j;
    float4 r0 = {res[0], res[1], res[2], res[3]};
    float4 r1 = {res[4], res[5], res[6], res[7]};
    *reinterpret_cast<float4*>(ob)     = r0;
    *reinterpret_cast<float4*>(ob + 4) = r1;
}

extern "C" void kernel_launch(void* const* d_in, const int* in_sizes, int n_in,
                              void* d_out, int out_size, void* d_ws, size_t ws_size,
                              hipStream_t stream) {
    const float* x     = (const float*)d_in[0];
    const float* w     = (const float*)d_in[1];
    const float* bias  = (const float*)d_in[2];
    const float* gamma = (const float*)d_in[3];
    const float* beta  = (const float*)d_in[4];
    float* out = (float*)d_out;

    float* stats = (float*)d_ws;                                   // 384 floats of sums
    __hip_bfloat16* y = (__hip_bfloat16*)((char*)d_ws + 4096);     // 154.1 MB bf16

    hipLaunchKernelGGL(zero_stats, dim3(1), dim3(256), 0, stream, stats);
    hipLaunchKernelGGL(conv_kernel, dim3(OCG * 392), dim3(256), 0, stream,
                       x, w, bias, y);
    hipLaunchKernelGGL(stats_kernel, dim3(B_ * OC), dim3(256), 0, stream, y, stats);
    hipLaunchKernelGGL(pool_kernel, dim3(B_ * OC * PH * 7 / 256), dim3(256), 0,
                       stream, y, stats, gamma, beta, out);
}

// Round 11
// 223.594 us; speedup vs baseline: 2.3890x; 1.0489x over previous
//
#include <hip/hip_runtime.h>
#include <hip/hip_bf16.h>
#include <math.h>

#define B_   32
#define CIN  3
#define H_   224
#define W_   224
#define OC   192
#define OH   112
#define OW   112
#define PH   56
#define PW   56
#define NSP  (B_*OH*OW)          // 401408 elements per channel for BN stats
#define PLANE (OH*OW)            // 12544
#define CB_STRIDE 68             // uint stride per oc row in LDS (16B aligned, bank-spread)

typedef __attribute__((ext_vector_type(8))) short bf16x8;   // 8 bf16 (4 VGPRs)
typedef __attribute__((ext_vector_type(4))) float f32x4;    // MFMA acc

static __device__ __forceinline__ unsigned short f2bf(float f) {
    __hip_bfloat16 h = __float2bfloat16(f);   // RNE
    return *reinterpret_cast<unsigned short*>(&h);
}
static __device__ __forceinline__ float bf_lo(unsigned int u) {
    unsigned int v = u << 16;
    return *reinterpret_cast<float*>(&v);
}
static __device__ __forceinline__ float bf_hi(unsigned int u) {
    unsigned int v = u & 0xffff0000u;
    return *reinterpret_cast<float*>(&v);
}

static __device__ __forceinline__ float fexp2(float x) {
#if __has_builtin(__builtin_amdgcn_exp2f)
    return __builtin_amdgcn_exp2f(x);
#else
    return exp2f(x);
#endif
}
static __device__ __forceinline__ float frcp(float x) {
#if __has_builtin(__builtin_amdgcn_rcpf)
    return __builtin_amdgcn_rcpf(x);
#else
    return 1.0f / x;
#endif
}

// tanh-form GELU via exp2 (+rcp). Unimodal (single min at x ~ -0.75).
static __device__ __forceinline__ float fast_gelu(float x) {
    float x2 = x * x;
    float inner = fmaf(0.044715f * x2, x, x);
    float e = fexp2(inner * 2.3022082f);      // 2*0.7978845608*log2(e)
    float r = frcp(1.0f + e);
    return x * (e * r);
}

// im2col tap for compile-time k: k = c*9 + r*3 + j; k==27 -> 1.0 (bias lane)
template<int K>
static __device__ __forceinline__ float tapT(const float* __restrict__ xb,
                                             int ihb, int iwb) {
    if constexpr (K == 27) { return 1.0f; }
    else if constexpr (K > 27) { return 0.0f; }
    else {
        constexpr int c = K / 9, r = (K % 9) / 3, j = K % 3;
        int ih = ihb + r, iw = iwb + j;
        bool v = ((unsigned)ih < (unsigned)H_) && ((unsigned)iw < (unsigned)W_);
        return v ? xb[(c * H_ + ih) * W_ + iw] : 0.0f;
    }
}

// ---------------- K0: zero the stats accumulators (ws is poisoned 0xAA) ----
__global__ void zero_stats(float* stats) {
    if (threadIdx.x < 384) stats[threadIdx.x] = 0.f;
}

// ---------------- K1: MFMA conv 3x3 s2 p1 + bias + fused BN stats ----------
// Block: 256 thr (4 waves) = 128 consecutive flat pixels of one batch x 192 oc.
// Wave: 32 px (2 M-tiles) x 12 oc-tiles = 24 x mfma_f32_16x16x32_bf16, K=27
// padded to 32; k=27 carries bias (A=1.0, B=bias). Stats reduced from C regs.
// C staged to LDS (bf16), stored as 256B-contiguous oc-rows (write amp 1).
__global__ __launch_bounds__(256) void conv_kernel(
    const float* __restrict__ x, const float* __restrict__ w,
    const float* __restrict__ bias, __hip_bfloat16* __restrict__ y,
    float* __restrict__ stats)
{
    __shared__ __align__(16) unsigned int cbuf[OC * CB_STRIDE];  // 52.2 KB
    __shared__ float ssum[2][4 * OC];                            // 6 KB

    int blk  = blockIdx.x;               // 3136 = 32 b x 98 chunks
    int b    = blk / 98;
    int pb   = (blk - b * 98) * 128;     // first flat pixel of block (within b)
    int tid  = threadIdx.x;
    int wv   = tid >> 6;
    int lane = tid & 63;
    int lo16 = lane & 15;
    int kg   = lane >> 4;                // k-group: k = kg*8 + j

    // ---- B fragments: 12 oc-tiles x (8 k-taps per lane) + bias at k=27 ----
    bf16x8 Bf[12];
    #pragma unroll
    for (int n = 0; n < 12; ++n) {
        int col = n * 16 + lo16;
        float tw[8];
        if (kg < 3) {
            int base = col * 27 + kg * 8;
            #pragma unroll
            for (int j = 0; j < 8; ++j) tw[j] = w[base + j];
        } else {
            tw[0] = w[col * 27 + 24];
            tw[1] = w[col * 27 + 25];
            tw[2] = w[col * 27 + 26];
            tw[3] = bias[col];
            tw[4] = 0.f; tw[5] = 0.f; tw[6] = 0.f; tw[7] = 0.f;
        }
        #pragma unroll
        for (int j = 0; j < 8; ++j) Bf[n][j] = (short)f2bf(tw[j]);
    }

    // ---- A fragments: 2 sub-tiles of 16 px, lane holds 8 k of its pixel ----
    const float* xb = x + (size_t)b * CIN * H_ * W_;
    bf16x8 Af[2];
    #pragma unroll
    for (int s = 0; s < 2; ++s) {
        int p  = pb + wv * 32 + s * 16 + lo16;   // flat pixel in [0,12544)
        int oh = p / OW;
        int ow = p - oh * OW;
        int ihb = 2 * oh - 1, iwb = 2 * ow - 1;
        float tv[8];
        if (kg == 0) {
            tv[0]=tapT<0>(xb,ihb,iwb); tv[1]=tapT<1>(xb,ihb,iwb);
            tv[2]=tapT<2>(xb,ihb,iwb); tv[3]=tapT<3>(xb,ihb,iwb);
            tv[4]=tapT<4>(xb,ihb,iwb); tv[5]=tapT<5>(xb,ihb,iwb);
            tv[6]=tapT<6>(xb,ihb,iwb); tv[7]=tapT<7>(xb,ihb,iwb);
        } else if (kg == 1) {
            tv[0]=tapT<8>(xb,ihb,iwb);  tv[1]=tapT<9>(xb,ihb,iwb);
            tv[2]=tapT<10>(xb,ihb,iwb); tv[3]=tapT<11>(xb,ihb,iwb);
            tv[4]=tapT<12>(xb,ihb,iwb); tv[5]=tapT<13>(xb,ihb,iwb);
            tv[6]=tapT<14>(xb,ihb,iwb); tv[7]=tapT<15>(xb,ihb,iwb);
        } else if (kg == 2) {
            tv[0]=tapT<16>(xb,ihb,iwb); tv[1]=tapT<17>(xb,ihb,iwb);
            tv[2]=tapT<18>(xb,ihb,iwb); tv[3]=tapT<19>(xb,ihb,iwb);
            tv[4]=tapT<20>(xb,ihb,iwb); tv[5]=tapT<21>(xb,ihb,iwb);
            tv[6]=tapT<22>(xb,ihb,iwb); tv[7]=tapT<23>(xb,ihb,iwb);
        } else {
            tv[0]=tapT<24>(xb,ihb,iwb); tv[1]=tapT<25>(xb,ihb,iwb);
            tv[2]=tapT<26>(xb,ihb,iwb); tv[3]=tapT<27>(xb,ihb,iwb);
            tv[4]=tapT<28>(xb,ihb,iwb); tv[5]=tapT<29>(xb,ihb,iwb);
            tv[6]=tapT<30>(xb,ihb,iwb); tv[7]=tapT<31>(xb,ihb,iwb);
        }
        #pragma unroll
        for (int j = 0; j < 8; ++j) Af[s][j] = (short)f2bf(tv[j]);
    }

    // ---- 24 MFMAs ----
    f32x4 acc0[12], acc1[12];
    #pragma unroll
    for (int n = 0; n < 12; ++n) {
        acc0[n] = (f32x4){0.f, 0.f, 0.f, 0.f};
        acc1[n] = (f32x4){0.f, 0.f, 0.f, 0.f};
    }
    #pragma unroll
    for (int n = 0; n < 12; ++n) {
        acc0[n] = __builtin_amdgcn_mfma_f32_16x16x32_bf16(Af[0], Bf[n], acc0[n], 0, 0, 0);
        acc1[n] = __builtin_amdgcn_mfma_f32_16x16x32_bf16(Af[1], Bf[n], acc1[n], 0, 0, 0);
    }

    // ---- fused stats: per-lane over 8 px of col oc, 2 shfl levels, LDS ----
    #pragma unroll
    for (int n = 0; n < 12; ++n) {
        float s = 0.f, s2 = 0.f;
        #pragma unroll
        for (int i = 0; i < 4; ++i) {
            float v = acc0[n][i]; s += v; s2 = fmaf(v, v, s2);
            v = acc1[n][i];       s += v; s2 = fmaf(v, v, s2);
        }
        s  += __shfl_xor(s, 16);  s  += __shfl_xor(s, 32);
        s2 += __shfl_xor(s2, 16); s2 += __shfl_xor(s2, 32);
        if (lane < 16) {
            ssum[0][wv * OC + n * 16 + lane] = s;
            ssum[1][wv * OC + n * 16 + lane] = s2;
        }
    }

    // ---- C -> LDS as bf16 pairs; row oc holds 128 px = 64 uints ----
    // C layout: col(oc)=lane&15, row(px)=kg*4+i; p_local = wv*32 + s*16 + row
    #pragma unroll
    for (int n = 0; n < 12; ++n) {
        int oc = n * 16 + lo16;
        int pu = wv * 16 + kg * 2;                       // uint idx, sub 0
        unsigned u01 = (unsigned)f2bf(acc0[n][0]) | ((unsigned)f2bf(acc0[n][1]) << 16);
        unsigned u23 = (unsigned)f2bf(acc0[n][2]) | ((unsigned)f2bf(acc0[n][3]) << 16);
        cbuf[oc * CB_STRIDE + pu]     = u01;
        cbuf[oc * CB_STRIDE + pu + 1] = u23;
        unsigned v01 = (unsigned)f2bf(acc1[n][0]) | ((unsigned)f2bf(acc1[n][1]) << 16);
        unsigned v23 = (unsigned)f2bf(acc1[n][2]) | ((unsigned)f2bf(acc1[n][3]) << 16);
        cbuf[oc * CB_STRIDE + pu + 8] = v01;             // sub 1: +16 px = +8 uints
        cbuf[oc * CB_STRIDE + pu + 9] = v23;
    }

    __syncthreads();

    // ---- coalesced global store: 16 lanes x uint4 = one 256B oc-row ----
    unsigned short* yus = reinterpret_cast<unsigned short*>(y);
    int ocr = tid >> 4;                                  // 0..15
    int ch  = tid & 15;                                  // 16B chunk in row
    #pragma unroll
    for (int ocb = 0; ocb < 12; ++ocb) {
        int oc = ocb * 16 + ocr;
        uint4 v = *reinterpret_cast<uint4*>(&cbuf[oc * CB_STRIDE + ch * 4]);
        *reinterpret_cast<uint4*>(
            yus + (size_t)(b * OC + oc) * PLANE + pb + ch * 8) = v;
    }

    // ---- stats: block-reduce 4 wave-partials, one atomic per channel ----
    // 384 work items on 256 threads: GRID-STRIDE (round-9 bug: `if (tid<384)`
    // left sumsq of oc 64..191 unwritten -> var<0 -> NaN).
    for (int i = tid; i < 2 * OC; i += 256) {
        int which = (i >= OC) ? 1 : 0;
        int oc = i - which * OC;
        float v = ssum[which][oc] + ssum[which][OC + oc] +
                  ssum[which][2 * OC + oc] + ssum[which][3 * OC + oc];
        atomicAdd(&stats[which * OC + oc], v);
    }
}

// ---------------- K2: min/max pool (1 row x 8 cols per thread) ------------
// Per input row: 3 aligned uint4 loads, running col min/max over 3 rows,
// then per output 1 affine + 2 fast-GELU (GELU unimodal).
__global__ __launch_bounds__(256) void pool_kernel(
    const __hip_bfloat16* __restrict__ y, const float* __restrict__ stats,
    const float* __restrict__ gamma, const float* __restrict__ beta,
    float* __restrict__ out)
{
    int g = blockIdx.x * 256 + threadIdx.x;     // 2,408,448 total
    int j = g % 7;                              // 8-col out group, lane-consecutive
    int t = g / 7;
    int ph = t % PH;
    int plane = t / PH;                         // b*OC + oc
    int oc = plane % OC;

    const unsigned short* py =
        reinterpret_cast<const unsigned short*>(y) + (size_t)plane * PLANE;

    float cmin[8], cmax[8];
    #pragma unroll
    for (int m = 0; m < 8; ++m) { cmin[m] = INFINITY; cmax[m] = -INFINITY; }

    #pragma unroll
    for (int rr = 0; rr < 3; ++rr) {
        int ih = 2 * ph - 1 + rr;               // <0 only for ph==0,rr==0
        if (ih >= 0) {
            const uint4* rp = reinterpret_cast<const uint4*>(py + ih * OW + 16 * j - 8);
            uint4 u0 = rp[0], u1 = rp[1], u2 = rp[2];
            float L[24];
            L[0]=bf_lo(u0.x); L[1]=bf_hi(u0.x); L[2]=bf_lo(u0.y); L[3]=bf_hi(u0.y);
            L[4]=bf_lo(u0.z); L[5]=bf_hi(u0.z); L[6]=bf_lo(u0.w); L[7]=bf_hi(u0.w);
            L[8]=bf_lo(u1.x); L[9]=bf_hi(u1.x); L[10]=bf_lo(u1.y); L[11]=bf_hi(u1.y);
            L[12]=bf_lo(u1.z); L[13]=bf_hi(u1.z); L[14]=bf_lo(u1.w); L[15]=bf_hi(u1.w);
            L[16]=bf_lo(u2.x); L[17]=bf_hi(u2.x); L[18]=bf_lo(u2.y); L[19]=bf_hi(u2.y);
            L[20]=bf_lo(u2.z); L[21]=bf_hi(u2.z); L[22]=bf_lo(u2.w); L[23]=bf_hi(u2.w);

            float l7min = (j == 0) ? INFINITY  : L[7];
            float l7max = (j == 0) ? -INFINITY : L[7];

            cmin[0] = fminf(cmin[0], fminf(fminf(l7min, L[8]), L[9]));
            cmax[0] = fmaxf(cmax[0], fmaxf(fmaxf(l7max, L[8]), L[9]));
            #pragma unroll
            for (int m = 1; m < 8; ++m) {
                cmin[m] = fminf(cmin[m], fminf(fminf(L[7+2*m], L[8+2*m]), L[9+2*m]));
                cmax[m] = fmaxf(cmax[m], fmaxf(fmaxf(L[7+2*m], L[8+2*m]), L[9+2*m]));
            }
        }
    }

    float mean = stats[oc] * (1.0f / (float)NSP);
    float var  = fmaf(-mean, mean, stats[OC + oc] * (1.0f / (float)NSP));
    float inv  = rsqrtf(var + 1e-5f);
    float sc   = gamma[oc] * inv;
    float sh   = fmaf(-mean, sc, beta[oc]);

    float res[8];
    #pragma unroll
    for (int m = 0; m < 8; ++m) {
        float lo = fmaf(cmin[m], sc, sh);
        float hi = fmaf(cmax[m], sc, sh);
        res[m] = fmaxf(fast_gelu(lo), fast_gelu(hi));
    }

    float* ob = out + (size_t)plane * (PH * PW) + ph * PW + 8 * j;
    float4 r0 = {res[0], res[1], res[2], res[3]};
    float4 r1 = {res[4], res[5], res[6], res[7]};
    *reinterpret_cast<float4*>(ob)     = r0;
    *reinterpret_cast<float4*>(ob + 4) = r1;
}

extern "C" void kernel_launch(void* const* d_in, const int* in_sizes, int n_in,
                              void* d_out, int out_size, void* d_ws, size_t ws_size,
                              hipStream_t stream) {
    const float* x     = (const float*)d_in[0];
    const float* w     = (const float*)d_in[1];
    const float* bias  = (const float*)d_in[2];
    const float* gamma = (const float*)d_in[3];
    const float* beta  = (const float*)d_in[4];
    float* out = (float*)d_out;

    float* stats = (float*)d_ws;                                   // 384 floats of sums
    __hip_bfloat16* y = (__hip_bfloat16*)((char*)d_ws + 4096);     // 154.1 MB bf16

    hipLaunchKernelGGL(zero_stats, dim3(1), dim3(384), 0, stream, stats);
    hipLaunchKernelGGL(conv_kernel, dim3(B_ * 98), dim3(256), 0, stream,
                       x, w, bias, y, stats);
    hipLaunchKernelGGL(pool_kernel, dim3(B_ * OC * PH * 7 / 256), dim3(256), 0,
                       stream, y, stats, gamma, beta, out);
}

// Round 12
// 222.694 us; speedup vs baseline: 2.3987x; 1.0040x over previous
//
#include <hip/hip_runtime.h>
#include <hip/hip_bf16.h>
#include <math.h>

#define B_   32
#define CIN  3
#define H_   224
#define W_   224
#define OC   192
#define OH   112
#define OW   112
#define PH   56
#define PW   56
#define NSP  (B_*OH*OW)          // 401408 elements per channel for BN stats
#define PLANE (OH*OW)            // 12544
#define CB_STRIDE 68             // uint stride per oc row in LDS (16B aligned, bank-spread)

typedef __attribute__((ext_vector_type(8))) short bf16x8;   // 8 bf16 (4 VGPRs)
typedef __attribute__((ext_vector_type(4))) float f32x4;    // MFMA acc

static __device__ __forceinline__ unsigned short f2bf(float f) {
    __hip_bfloat16 h = __float2bfloat16(f);   // RNE
    return *reinterpret_cast<unsigned short*>(&h);
}
static __device__ __forceinline__ float bf_lo(unsigned int u) {
    unsigned int v = u << 16;
    return *reinterpret_cast<float*>(&v);
}
static __device__ __forceinline__ float bf_hi(unsigned int u) {
    unsigned int v = u & 0xffff0000u;
    return *reinterpret_cast<float*>(&v);
}

static __device__ __forceinline__ float fexp2(float x) {
#if __has_builtin(__builtin_amdgcn_exp2f)
    return __builtin_amdgcn_exp2f(x);
#else
    return exp2f(x);
#endif
}
static __device__ __forceinline__ float frcp(float x) {
#if __has_builtin(__builtin_amdgcn_rcpf)
    return __builtin_amdgcn_rcpf(x);
#else
    return 1.0f / x;
#endif
}

// tanh-form GELU via exp2 (+rcp). Unimodal (single min at x ~ -0.75).
static __device__ __forceinline__ float fast_gelu(float x) {
    float x2 = x * x;
    float inner = fmaf(0.044715f * x2, x, x);
    float e = fexp2(inner * 2.3022082f);      // 2*0.7978845608*log2(e)
    float r = frcp(1.0f + e);
    return x * (e * r);
}

// im2col tap for compile-time k: k = c*9 + r*3 + j; k==27 -> 1.0 (bias lane)
template<int K>
static __device__ __forceinline__ float tapT(const float* __restrict__ xb,
                                             int ihb, int iwb) {
    if constexpr (K == 27) { return 1.0f; }
    else if constexpr (K > 27) { return 0.0f; }
    else {
        constexpr int c = K / 9, r = (K % 9) / 3, j = K % 3;
        int ih = ihb + r, iw = iwb + j;
        bool v = ((unsigned)ih < (unsigned)H_) && ((unsigned)iw < (unsigned)W_);
        return v ? xb[(c * H_ + ih) * W_ + iw] : 0.0f;
    }
}

// ---------------- K0: zero stats + precompute B fragments ONCE -------------
// Round-11 lesson: building B frags per-thread in conv = 96 scattered scalar
// loads/thread (64 cache lines per wave instr) -> 127us. Build them once here;
// conv then loads bfrag[n*64+lane] = lane-consecutive uint4 (coalesced,
// L2/L3-broadcast, 12 KB total).
__global__ void prep_kernel(const float* __restrict__ w,
                            const float* __restrict__ bias,
                            float* __restrict__ stats, uint4* __restrict__ bfrag) {
    int t = threadIdx.x;                 // 768 threads
    if (t < 384) stats[t] = 0.f;
    int n = t >> 6, lane = t & 63;
    int lo16 = lane & 15, kg = lane >> 4;
    int col = n * 16 + lo16;
    float tw[8];
    if (kg < 3) {
        int base = col * 27 + kg * 8;
        #pragma unroll
        for (int j = 0; j < 8; ++j) tw[j] = w[base + j];
    } else {
        tw[0] = w[col * 27 + 24];
        tw[1] = w[col * 27 + 25];
        tw[2] = w[col * 27 + 26];
        tw[3] = bias[col];
        tw[4] = 0.f; tw[5] = 0.f; tw[6] = 0.f; tw[7] = 0.f;
    }
    uint4 u;
    u.x = (unsigned)f2bf(tw[0]) | ((unsigned)f2bf(tw[1]) << 16);
    u.y = (unsigned)f2bf(tw[2]) | ((unsigned)f2bf(tw[3]) << 16);
    u.z = (unsigned)f2bf(tw[4]) | ((unsigned)f2bf(tw[5]) << 16);
    u.w = (unsigned)f2bf(tw[6]) | ((unsigned)f2bf(tw[7]) << 16);
    bfrag[t] = u;
}

// ---------------- K1: MFMA conv 3x3 s2 p1 + bias + fused BN stats ----------
// Block: 256 thr (4 waves) = 128 consecutive flat pixels of one batch x 192 oc.
// Wave: 32 px x 12 oc-tiles = 24 x mfma_f32_16x16x32_bf16 (K=27 padded to 32,
// k=27 = bias via A=1.0). B frags: coalesced uint4 from precomputed bfrag.
// C staged through a 96-channel LDS buffer in 2 phases (26KB -> 4 blocks/CU).
__global__ __launch_bounds__(256) void conv_kernel(
    const float* __restrict__ x, const uint4* __restrict__ bfrag,
    __hip_bfloat16* __restrict__ y, float* __restrict__ stats)
{
    __shared__ __align__(16) unsigned int cbuf[96 * CB_STRIDE];  // 26.1 KB
    __shared__ float ssum[2][4 * OC];                            // 6 KB

    int blk  = blockIdx.x;               // 3136 = 32 b x 98 chunks
    int b    = blk / 98;
    int pb   = (blk - b * 98) * 128;     // first flat pixel of block (within b)
    int tid  = threadIdx.x;
    int wv   = tid >> 6;
    int lane = tid & 63;
    int lo16 = lane & 15;
    int kg   = lane >> 4;                // k-group: k = kg*8 + j

    // ---- A fragments: 2 sub-tiles of 16 px, lane holds 8 k of its pixel ----
    const float* xb = x + (size_t)b * CIN * H_ * W_;
    bf16x8 Af[2];
    #pragma unroll
    for (int s = 0; s < 2; ++s) {
        int p  = pb + wv * 32 + s * 16 + lo16;   // flat pixel in [0,12544)
        int oh = p / OW;
        int ow = p - oh * OW;
        int ihb = 2 * oh - 1, iwb = 2 * ow - 1;
        float tv[8];
        if (kg == 0) {
            tv[0]=tapT<0>(xb,ihb,iwb); tv[1]=tapT<1>(xb,ihb,iwb);
            tv[2]=tapT<2>(xb,ihb,iwb); tv[3]=tapT<3>(xb,ihb,iwb);
            tv[4]=tapT<4>(xb,ihb,iwb); tv[5]=tapT<5>(xb,ihb,iwb);
            tv[6]=tapT<6>(xb,ihb,iwb); tv[7]=tapT<7>(xb,ihb,iwb);
        } else if (kg == 1) {
            tv[0]=tapT<8>(xb,ihb,iwb);  tv[1]=tapT<9>(xb,ihb,iwb);
            tv[2]=tapT<10>(xb,ihb,iwb); tv[3]=tapT<11>(xb,ihb,iwb);
            tv[4]=tapT<12>(xb,ihb,iwb); tv[5]=tapT<13>(xb,ihb,iwb);
            tv[6]=tapT<14>(xb,ihb,iwb); tv[7]=tapT<15>(xb,ihb,iwb);
        } else if (kg == 2) {
            tv[0]=tapT<16>(xb,ihb,iwb); tv[1]=tapT<17>(xb,ihb,iwb);
            tv[2]=tapT<18>(xb,ihb,iwb); tv[3]=tapT<19>(xb,ihb,iwb);
            tv[4]=tapT<20>(xb,ihb,iwb); tv[5]=tapT<21>(xb,ihb,iwb);
            tv[6]=tapT<22>(xb,ihb,iwb); tv[7]=tapT<23>(xb,ihb,iwb);
        } else {
            tv[0]=tapT<24>(xb,ihb,iwb); tv[1]=tapT<25>(xb,ihb,iwb);
            tv[2]=tapT<26>(xb,ihb,iwb); tv[3]=tapT<27>(xb,ihb,iwb);
            tv[4]=tapT<28>(xb,ihb,iwb); tv[5]=tapT<29>(xb,ihb,iwb);
            tv[6]=tapT<30>(xb,ihb,iwb); tv[7]=tapT<31>(xb,ihb,iwb);
        }
        #pragma unroll
        for (int j = 0; j < 8; ++j) Af[s][j] = (short)f2bf(tv[j]);
    }

    // ---- 24 MFMAs, B loaded coalesced per tile (short lifetime) ----
    f32x4 acc0[12], acc1[12];
    #pragma unroll
    for (int n = 0; n < 12; ++n) {
        acc0[n] = (f32x4){0.f, 0.f, 0.f, 0.f};
        acc1[n] = (f32x4){0.f, 0.f, 0.f, 0.f};
    }
    #pragma unroll
    for (int n = 0; n < 12; ++n) {
        uint4 bu = bfrag[n * 64 + lane];
        bf16x8 Bf = *reinterpret_cast<bf16x8*>(&bu);
        acc0[n] = __builtin_amdgcn_mfma_f32_16x16x32_bf16(Af[0], Bf, acc0[n], 0, 0, 0);
        acc1[n] = __builtin_amdgcn_mfma_f32_16x16x32_bf16(Af[1], Bf, acc1[n], 0, 0, 0);
    }

    // ---- fused stats: per-lane over 8 px of col oc, 2 shfl levels, LDS ----
    #pragma unroll
    for (int n = 0; n < 12; ++n) {
        float s = 0.f, s2 = 0.f;
        #pragma unroll
        for (int i = 0; i < 4; ++i) {
            float v = acc0[n][i]; s += v; s2 = fmaf(v, v, s2);
            v = acc1[n][i];       s += v; s2 = fmaf(v, v, s2);
        }
        s  += __shfl_xor(s, 16);  s  += __shfl_xor(s, 32);
        s2 += __shfl_xor(s2, 16); s2 += __shfl_xor(s2, 32);
        if (lane < 16) {
            ssum[0][wv * OC + n * 16 + lane] = s;
            ssum[1][wv * OC + n * 16 + lane] = s2;
        }
    }

    // ---- C -> LDS -> coalesced store, 2 phases of 96 channels ----
    unsigned short* yus = reinterpret_cast<unsigned short*>(y);
    int ocr = tid >> 4;                                  // 0..15
    int ch  = tid & 15;                                  // 16B chunk in row
    #pragma unroll
    for (int ph = 0; ph < 2; ++ph) {
        __syncthreads();                                 // cbuf free of prior readers
        #pragma unroll
        for (int nn = 0; nn < 6; ++nn) {
            int n   = ph * 6 + nn;
            int ocl = nn * 16 + lo16;                    // local row 0..95
            int pu  = wv * 16 + kg * 2;
            unsigned u01 = (unsigned)f2bf(acc0[n][0]) | ((unsigned)f2bf(acc0[n][1]) << 16);
            unsigned u23 = (unsigned)f2bf(acc0[n][2]) | ((unsigned)f2bf(acc0[n][3]) << 16);
            cbuf[ocl * CB_STRIDE + pu]     = u01;
            cbuf[ocl * CB_STRIDE + pu + 1] = u23;
            unsigned v01 = (unsigned)f2bf(acc1[n][0]) | ((unsigned)f2bf(acc1[n][1]) << 16);
            unsigned v23 = (unsigned)f2bf(acc1[n][2]) | ((unsigned)f2bf(acc1[n][3]) << 16);
            cbuf[ocl * CB_STRIDE + pu + 8] = v01;        // sub 1: +16 px
            cbuf[ocl * CB_STRIDE + pu + 9] = v23;
        }
        __syncthreads();
        #pragma unroll
        for (int ocb = 0; ocb < 6; ++ocb) {
            int ocl = ocb * 16 + ocr;
            int oc  = ph * 96 + ocl;
            uint4 v = *reinterpret_cast<uint4*>(&cbuf[ocl * CB_STRIDE + ch * 4]);
            *reinterpret_cast<uint4*>(
                yus + (size_t)(b * OC + oc) * PLANE + pb + ch * 8) = v;
        }
    }

    // ---- stats: block-reduce 4 wave-partials (grid-stride over 384) ----
    for (int i = tid; i < 2 * OC; i += 256) {
        int which = (i >= OC) ? 1 : 0;
        int oc = i - which * OC;
        float v = ssum[which][oc] + ssum[which][OC + oc] +
                  ssum[which][2 * OC + oc] + ssum[which][3 * OC + oc];
        atomicAdd(&stats[which * OC + oc], v);
    }
}

// ---------------- K2: min/max pool (1 row x 8 cols per thread) ------------
// Per input row: 3 aligned uint4 loads, running col min/max over 3 rows,
// then per output 1 affine + 2 fast-GELU (GELU unimodal).
__global__ __launch_bounds__(256) void pool_kernel(
    const __hip_bfloat16* __restrict__ y, const float* __restrict__ stats,
    const float* __restrict__ gamma, const float* __restrict__ beta,
    float* __restrict__ out)
{
    int g = blockIdx.x * 256 + threadIdx.x;     // 2,408,448 total
    int j = g % 7;                              // 8-col out group, lane-consecutive
    int t = g / 7;
    int ph = t % PH;
    int plane = t / PH;                         // b*OC + oc
    int oc = plane % OC;

    const unsigned short* py =
        reinterpret_cast<const unsigned short*>(y) + (size_t)plane * PLANE;

    float cmin[8], cmax[8];
    #pragma unroll
    for (int m = 0; m < 8; ++m) { cmin[m] = INFINITY; cmax[m] = -INFINITY; }

    #pragma unroll
    for (int rr = 0; rr < 3; ++rr) {
        int ih = 2 * ph - 1 + rr;               // <0 only for ph==0,rr==0
        if (ih >= 0) {
            const uint4* rp = reinterpret_cast<const uint4*>(py + ih * OW + 16 * j - 8);
            uint4 u0 = rp[0], u1 = rp[1], u2 = rp[2];
            float L[24];
            L[0]=bf_lo(u0.x); L[1]=bf_hi(u0.x); L[2]=bf_lo(u0.y); L[3]=bf_hi(u0.y);
            L[4]=bf_lo(u0.z); L[5]=bf_hi(u0.z); L[6]=bf_lo(u0.w); L[7]=bf_hi(u0.w);
            L[8]=bf_lo(u1.x); L[9]=bf_hi(u1.x); L[10]=bf_lo(u1.y); L[11]=bf_hi(u1.y);
            L[12]=bf_lo(u1.z); L[13]=bf_hi(u1.z); L[14]=bf_lo(u1.w); L[15]=bf_hi(u1.w);
            L[16]=bf_lo(u2.x); L[17]=bf_hi(u2.x); L[18]=bf_lo(u2.y); L[19]=bf_hi(u2.y);
            L[20]=bf_lo(u2.z); L[21]=bf_hi(u2.z); L[22]=bf_lo(u2.w); L[23]=bf_hi(u2.w);

            float l7min = (j == 0) ? INFINITY  : L[7];
            float l7max = (j == 0) ? -INFINITY : L[7];

            cmin[0] = fminf(cmin[0], fminf(fminf(l7min, L[8]), L[9]));
            cmax[0] = fmaxf(cmax[0], fmaxf(fmaxf(l7max, L[8]), L[9]));
            #pragma unroll
            for (int m = 1; m < 8; ++m) {
                cmin[m] = fminf(cmin[m], fminf(fminf(L[7+2*m], L[8+2*m]), L[9+2*m]));
                cmax[m] = fmaxf(cmax[m], fmaxf(fmaxf(L[7+2*m], L[8+2*m]), L[9+2*m]));
            }
        }
    }

    float mean = stats[oc] * (1.0f / (float)NSP);
    float var  = fmaf(-mean, mean, stats[OC + oc] * (1.0f / (float)NSP));
    float inv  = rsqrtf(var + 1e-5f);
    float sc   = gamma[oc] * inv;
    float sh   = fmaf(-mean, sc, beta[oc]);

    float res[8];
    #pragma unroll
    for (int m = 0; m < 8; ++m) {
        float lo = fmaf(cmin[m], sc, sh);
        float hi = fmaf(cmax[m], sc, sh);
        res[m] = fmaxf(fast_gelu(lo), fast_gelu(hi));
    }

    float* ob = out + (size_t)plane * (PH * PW) + ph * PW + 8 * j;
    float4 r0 = {res[0], res[1], res[2], res[3]};
    float4 r1 = {res[4], res[5], res[6], res[7]};
    *reinterpret_cast<float4*>(ob)     = r0;
    *reinterpret_cast<float4*>(ob + 4) = r1;
}

extern "C" void kernel_launch(void* const* d_in, const int* in_sizes, int n_in,
                              void* d_out, int out_size, void* d_ws, size_t ws_size,
                              hipStream_t stream) {
    const float* x     = (const float*)d_in[0];
    const float* w     = (const float*)d_in[1];
    const float* bias  = (const float*)d_in[2];
    const float* gamma = (const float*)d_in[3];
    const float* beta  = (const float*)d_in[4];
    float* out = (float*)d_out;

    float* stats = (float*)d_ws;                                   // 384 floats of sums
    uint4* bfrag = (uint4*)((char*)d_ws + 2048);                   // 12 KB B fragments
    __hip_bfloat16* y = (__hip_bfloat16*)((char*)d_ws + 16384);    // 154.1 MB bf16

    hipLaunchKernelGGL(prep_kernel, dim3(1), dim3(768), 0, stream,
                       w, bias, stats, bfrag);
    hipLaunchKernelGGL(conv_kernel, dim3(B_ * 98), dim3(256), 0, stream,
                       x, bfrag, y, stats);
    hipLaunchKernelGGL(pool_kernel, dim3(B_ * OC * PH * 7 / 256), dim3(256), 0,
                       stream, y, stats, gamma, beta, out);
}